// Round 13
// baseline (948.226 us; speedup 1.0000x reference)
//
#include <hip/hip_runtime.h>
#include <math.h>
#include <stdint.h>

#define D2 2048

typedef int v4i __attribute__((ext_vector_type(4)));
typedef int v16i __attribute__((ext_vector_type(16)));
typedef float v4f __attribute__((ext_vector_type(4)));
typedef float v2f __attribute__((ext_vector_type(2)));

struct Ptrs8 { const float* p[8]; };
struct RowMap { int seg, jump, off; };

enum { QW_Q = 0, QW_OUT = 1, QW_ADDQ = 2, QW_ADDOUT = 3, QW_I = 4, QW_F = 5, QW_G = 6, QW_O = 7 };

__device__ __forceinline__ int rmap(RowMap m, int r) {
  return (r / m.seg) * m.jump + (r % m.seg) + m.off;
}

__device__ __forceinline__ void gload16(const void* g, void* l) {
  __builtin_amdgcn_global_load_lds((__attribute__((address_space(1))) void*)g,
                                   (__attribute__((address_space(3))) void*)l, 16, 0, 0);
}

__device__ __forceinline__ float fsig(float x) {
  return __builtin_amdgcn_rcpf(1.0f + __expf(-x));
}

template <bool NT>
__device__ __forceinline__ void stf(float* p, float v) {
  if (NT) __builtin_nontemporal_store(v, p);
  else *p = v;
}

__device__ __forceinline__ v4f ldnt4(const float* p) {
  return __builtin_nontemporal_load((const v4f*)p);
}
__device__ __forceinline__ v2f ldnt2(const float* p) {
  return __builtin_nontemporal_load((const v2f*)p);
}

// Slot swizzle for 64B LDS rows (involution on stage+read sides).
__device__ __forceinline__ int swz(int r) { return ((r >> 1) & 3) ^ ((r >> 3) & 3); }

// XCD-chunked bijective grid swizzles, n-fast within a chunk.
__device__ __forceinline__ void gswz16(int nM, int& mb, int& nb) {  // nN = 16
  int bid = blockIdx.x;
  int wg = (bid & 7) * (nM << 1) + (bid >> 3);
  mb = wg >> 4;
  nb = wg & 15;
}
__device__ __forceinline__ void gswz8(int nM, int& mb, int& nb) {  // nN = 8
  int bid = blockIdx.x;
  int wg = (bid & 7) * nM + (bid >> 3);
  mb = wg >> 3;
  nb = wg & 7;
}

// ---------------- weight quantization ----------------
__global__ __launch_bounds__(256) void k_wabs(Ptrs8 wsrc, double* part) {
  int m = blockIdx.y;
  const float* w0 = wsrc.p[m] + (size_t)blockIdx.x * 4096 + threadIdx.x * 16;
  double s = 0.0;
#pragma unroll
  for (int j = 0; j < 4; ++j) {
    v4f v = ldnt4(w0 + j * 4);
    s += (double)fabsf(v[0]) + (double)fabsf(v[1]) + (double)fabsf(v[2]) + (double)fabsf(v[3]);
  }
#pragma unroll
  for (int o = 32; o; o >>= 1) s += __shfl_down(s, o);
  __shared__ double red[4];
  if ((threadIdx.x & 63) == 0) red[threadIdx.x >> 6] = s;
  __syncthreads();
  if (threadIdx.x == 0) part[(size_t)m * 1024 + blockIdx.x] = red[0] + red[1] + red[2] + red[3];
}

__global__ __launch_bounds__(256) void k_wmean(const double* part, double* wqs, float* wmul) {
  int m = blockIdx.x, t = threadIdx.x;
  const double* p = part + (size_t)m * 1024;
  double s = p[t] + p[t + 256] + p[t + 512] + p[t + 768];
#pragma unroll
  for (int o = 32; o; o >>= 1) s += __shfl_down(s, o);
  __shared__ double red[4];
  if ((t & 63) == 0) red[t >> 6] = s;
  __syncthreads();
  if (t == 0) {
    double mean = (red[0] + red[1] + red[2] + red[3]) * (1.0 / 4194304.0);
    double cl = mean > 1e-5 ? mean : 1e-5;
    wqs[m] = 1.0 / cl;
    wmul[m] = (float)cl;
  }
}

__global__ __launch_bounds__(256) void k_wquant(Ptrs8 wsrc, const double* wqs, int8_t* wq) {
  int m = blockIdx.y;
  double qs = wqs[m];
  size_t base = (size_t)blockIdx.x * 4096 + threadIdx.x * 16;
  const float* w0 = wsrc.p[m] + base;
  union { int8_t b[16]; int4 v; } u;
#pragma unroll
  for (int j = 0; j < 4; ++j) {
    v4f v = ldnt4(w0 + j * 4);
#pragma unroll
    for (int c = 0; c < 4; ++c) {
      int q = (int)rint((double)v[c] * qs);
      q = q > 1 ? 1 : (q < -1 ? -1 : q);
      u.b[j * 4 + c] = (int8_t)q;
    }
  }
  *(int4*)(wq + (size_t)m * 4194304 + base) = u.v;
}

// ---------------- activation rmsnorm + int8 quant (input dead after read -> NT loads) -------
__global__ __launch_bounds__(256) void k_actq(const float* __restrict__ x, int8_t* __restrict__ q,
                                              float* __restrict__ inv) {
  int row = blockIdx.x, t = threadIdx.x;
  const float* xr = x + (size_t)row * D2 + (size_t)t * 8;
  v4f a = ldnt4(xr);
  v4f b = ldnt4(xr + 4);
  float v[8] = {a[0], a[1], a[2], a[3], b[0], b[1], b[2], b[3]};
  float ss = 0.f, ma = 0.f;
#pragma unroll
  for (int j = 0; j < 8; ++j) { ss += v[j] * v[j]; ma = fmaxf(ma, fabsf(v[j])); }
#pragma unroll
  for (int o = 32; o; o >>= 1) { ss += __shfl_down(ss, o); ma = fmaxf(ma, __shfl_down(ma, o)); }
  __shared__ float rs[4], rm[4], bc[2];
  if ((t & 63) == 0) { rs[t >> 6] = ss; rm[t >> 6] = ma; }
  __syncthreads();
  if (t == 0) {
    float S = rs[0] + rs[1] + rs[2] + rs[3];
    float M = fmaxf(fmaxf(rm[0], rm[1]), fmaxf(rm[2], rm[3]));
    float r = 1.0f / sqrtf(S * (1.0f / 2048.0f) + 1e-5f);
    float mx = fmaxf(M * r, 1e-5f);
    bc[0] = r;
    bc[1] = 127.0f / mx;
    inv[row] = mx * (1.0f / 127.0f);
  }
  __syncthreads();
  float r = bc[0], s = bc[1];
  union { int8_t b8[8]; int2 p2; } u;
#pragma unroll
  for (int j = 0; j < 8; ++j) {
    float xn = v[j] * r;
    int qq = (int)rintf(xn * s);
    qq = qq > 127 ? 127 : (qq < -128 ? -128 : qq);
    u.b8[j] = (int8_t)qq;
  }
  ((int2*)(q + (size_t)row * D2))[t] = u.p2;
}

// ---------------- shared pipeline macros ----------------
#define SYNC_PIPE(N)                                          \
  do {                                                        \
    __builtin_amdgcn_sched_barrier(0);                        \
    asm volatile("s_waitcnt vmcnt(" #N ")" ::: "memory");     \
    __builtin_amdgcn_sched_barrier(0);                        \
    __builtin_amdgcn_s_barrier();                             \
    __builtin_amdgcn_sched_barrier(0);                        \
  } while (0)

// ------- 128x256 int8 GEMM main loop: wave tile 64x128, triple buffer, counted vmcnt -------
__device__ __forceinline__ void gemm_mainloop(const int8_t* __restrict__ Aq,
                                              const int8_t* __restrict__ Wq, int ga0, int ga1,
                                              int n0, int t, int8_t* lds, v16i acc[2][4]) {
  const int wid = t >> 6, lane = t & 63;
  const int wr = wid >> 1, wc = wid & 1, am = lane & 31, g = lane >> 5;
  const int arow = t >> 2;
  const int achk = ((t & 3) ^ swz(arow)) * 16;
  const int8_t* agp0 = Aq + (size_t)ga0 * 2048 + achk;
  const int8_t* agp1 = Aq + (size_t)ga1 * 2048 + achk;
  const int8_t* bgp0 = Wq + (size_t)(n0 + arow) * 2048 + achk;
  const int8_t* bgp1 = Wq + (size_t)(n0 + 64 + arow) * 2048 + achk;
  const int8_t* bgp2 = Wq + (size_t)(n0 + 128 + arow) * 2048 + achk;
  const int8_t* bgp3 = Wq + (size_t)(n0 + 192 + arow) * 2048 + achk;

#define STAGEW(B)                                                \
  do {                                                           \
    gload16(agp0, lds + (B) + wid * 1024);                       \
    gload16(agp1, lds + (B) + 4096 + wid * 1024);                \
    gload16(bgp0, lds + (B) + 8192 + wid * 1024);                \
    gload16(bgp1, lds + (B) + 12288 + wid * 1024);               \
    gload16(bgp2, lds + (B) + 16384 + wid * 1024);               \
    gload16(bgp3, lds + (B) + 20480 + wid * 1024);               \
    agp0 += 64; agp1 += 64;                                      \
    bgp0 += 64; bgp1 += 64; bgp2 += 64; bgp3 += 64;              \
  } while (0)

#define COMPUTEW(B)                                                                         \
  do {                                                                                      \
    _Pragma("unroll") for (int kk = 0; kk < 2; ++kk) {                                      \
      v4i af[2], bf[4];                                                                     \
      _Pragma("unroll") for (int mi = 0; mi < 2; ++mi) {                                    \
        int r = wr * 64 + mi * 32 + am;                                                     \
        int slot = ((kk << 1) | g) ^ swz(r);                                                \
        af[mi] = *(const v4i*)(lds + (B) + r * 64 + slot * 16);                             \
      }                                                                                     \
      _Pragma("unroll") for (int ni = 0; ni < 4; ++ni) {                                    \
        int rb = wc * 128 + ni * 32 + am;                                                   \
        int slotb = ((kk << 1) | g) ^ swz(rb);                                              \
        bf[ni] = *(const v4i*)(lds + (B) + 8192 + rb * 64 + slotb * 16);                    \
      }                                                                                     \
      _Pragma("unroll") for (int mi = 0; mi < 2; ++mi)                                      \
        _Pragma("unroll") for (int ni = 0; ni < 4; ++ni)                                    \
          acc[mi][ni] =                                                                     \
              __builtin_amdgcn_mfma_i32_32x32x32_i8(af[mi], bf[ni], acc[mi][ni], 0, 0, 0);  \
    }                                                                                       \
  } while (0)

  STAGEW(0);
  STAGEW(24576);
  STAGEW(49152);
  SYNC_PIPE(12);
#pragma unroll 1
  for (int tt = 0; tt < 30; tt += 3) {
    COMPUTEW(0);
    SYNC_PIPE(6);
    if (tt + 3 < 32) STAGEW(0);
    COMPUTEW(24576);
    SYNC_PIPE(6);
    if (tt + 4 < 32) STAGEW(24576);
    COMPUTEW(49152);
    SYNC_PIPE(6);
    if (tt + 5 < 32) STAGEW(49152);
  }
  COMPUTEW(0);
  SYNC_PIPE(0);
  COMPUTEW(24576);
#undef STAGEW
#undef COMPUTEW
}

template <bool NT>
__device__ __forceinline__ void gemm_body(const int8_t* Aq, const float* ainv, const int8_t* Wq,
                                          const float* wmul, int widx, float* C, RowMap inm,
                                          RowMap outm, int m0, int n0, int t, int8_t* lds) {
  int lane = t & 63, wid = t >> 6;
  int wr = wid >> 1, wc = wid & 1;
  int am = lane & 31, g = lane >> 5;
  int ga0 = rmap(inm, m0 + (t >> 2));
  int ga1 = rmap(inm, m0 + 64 + (t >> 2));

  v16i acc[2][4] = {};
  gemm_mainloop(Aq, Wq, ga0, ga1, n0, t, lds, acc);

  float wm = wmul[widx];
#pragma unroll
  for (int mi = 0; mi < 2; ++mi) {
#pragma unroll
    for (int q = 0; q < 16; ++q) {
      int rin = wr * 64 + mi * 32 + (q & 3) + ((q >> 2) * 8) + g * 4;
      int ra = rmap(inm, m0 + rin);
      int rc = rmap(outm, m0 + rin);
      float s = ainv[ra] * wm;
#pragma unroll
      for (int ni = 0; ni < 4; ++ni) {
        stf<NT>(&C[(size_t)rc * 2048 + n0 + wc * 128 + ni * 32 + am], (float)acc[mi][ni][q] * s);
      }
    }
  }
}

template <bool NT>
__global__ __launch_bounds__(256) void k_gemm(const int8_t* __restrict__ Aq,
                                              const float* __restrict__ ainv,
                                              const int8_t* __restrict__ Wq,
                                              const float* __restrict__ wmul, int widx,
                                              float* __restrict__ C, RowMap inm, RowMap outm,
                                              int nM) {
  __shared__ __align__(16) int8_t lds[73728];
  int mb, nb;
  gswz8(nM, mb, nb);
  gemm_body<NT>(Aq, ainv, Wq, wmul, widx, C, inm, outm, mb * 128, nb * 256, threadIdx.x, lds);
}

// Merged pair of GEMMs sharing one grid (big set 0 for mb<nM0, small set 1 after).
template <bool NT>
__global__ __launch_bounds__(256) void k_gemm2(const int8_t* __restrict__ Aq,
                                               const float* __restrict__ ainv,
                                               const int8_t* __restrict__ W0, int w0idx,
                                               RowMap inm0, RowMap outm0, float* __restrict__ C0,
                                               int nM0,
                                               const int8_t* __restrict__ W1, int w1idx,
                                               RowMap inm1, RowMap outm1, float* __restrict__ C1,
                                               int nM1, const float* __restrict__ wmul) {
  __shared__ __align__(16) int8_t lds[73728];
  int mb, nb;
  gswz8(nM0 + nM1, mb, nb);
  if (mb < nM0) {
    gemm_body<NT>(Aq, ainv, W0, wmul, w0idx, C0, inm0, outm0, mb * 128, nb * 256, threadIdx.x,
                  lds);
  } else {
    gemm_body<NT>(Aq, ainv, W1, wmul, w1idx, C1, inm1, outm1, (mb - nM0) * 128, nb * 256,
                  threadIdx.x, lds);
  }
}

// ------------- fused i+f GEMM + 64-row chunk-summary epilogue -------------
// LDS 72KB: 3 buffers x {A 8KB, Bi 8KB, Bf 8KB}. Counted vmcnt(6) steady state.
// Epilogue: a=sig(fv); ig=silu(iv)*(1-a); NT stores. Chunk summaries (P=prod a, H=h from 0)
// for TWO 64-row chunks per tile: per-lane 4-row runs -> LDS [seg][col] (seg s = rows
// [4s,4s+4)) -> 128 threads compose segs 0..15 (chunk 2*lt) and 16..31 (chunk 2*lt+1).
// 4608 rows/batch = 72 chunks of 64.
__global__ __launch_bounds__(256) void k_gemm_if(const int8_t* __restrict__ Aq,
                                                 const float* __restrict__ ainv,
                                                 const int8_t* __restrict__ Wi,
                                                 const int8_t* __restrict__ Wf,
                                                 const float* __restrict__ wmul,
                                                 float* __restrict__ IG, float* __restrict__ AD,
                                                 float* __restrict__ chA, float* __restrict__ chH,
                                                 int nM) {
  __shared__ __align__(16) int8_t lds[73728];
  int mb, nb;
  gswz16(nM, mb, nb);
  int m0 = mb * 128, n0 = nb * 128;
  int t = threadIdx.x;
  const int wid = t >> 6, lane = t & 63;
  const int wr = wid >> 1, wc = wid & 1, am = lane & 31, g = lane >> 5;
  const int arow = t >> 2;
  const int achk = ((t & 3) ^ swz(arow)) * 16;
  const int8_t* agp0 = Aq + (size_t)(m0 + arow) * 2048 + achk;
  const int8_t* agp1 = Aq + (size_t)(m0 + 64 + arow) * 2048 + achk;
  const int8_t* bip0 = Wi + (size_t)(n0 + arow) * 2048 + achk;
  const int8_t* bip1 = Wi + (size_t)(n0 + 64 + arow) * 2048 + achk;
  const int8_t* bfp0 = Wf + (size_t)(n0 + arow) * 2048 + achk;
  const int8_t* bfp1 = Wf + (size_t)(n0 + 64 + arow) * 2048 + achk;

  v16i acci[2][2] = {};
  v16i accf[2][2] = {};

#define STAGE_IF(B)                                                                   \
  do {                                                                                \
    gload16(agp0, lds + (B) + wid * 1024);                                            \
    gload16(agp1, lds + (B) + 4096 + wid * 1024);                                     \
    gload16(bip0, lds + (B) + 8192 + wid * 1024);                                     \
    gload16(bip1, lds + (B) + 12288 + wid * 1024);                                    \
    gload16(bfp0, lds + (B) + 16384 + wid * 1024);                                    \
    gload16(bfp1, lds + (B) + 20480 + wid * 1024);                                    \
    agp0 += 64; agp1 += 64; bip0 += 64; bip1 += 64; bfp0 += 64; bfp1 += 64;           \
  } while (0)

#define COMPUTE_IF(B)                                                                       \
  do {                                                                                      \
    _Pragma("unroll") for (int kk = 0; kk < 2; ++kk) {                                      \
      v4i af[2], bfi[2], bff[2];                                                            \
      _Pragma("unroll") for (int mi = 0; mi < 2; ++mi) {                                    \
        int r = wr * 64 + mi * 32 + am;                                                     \
        int slot = ((kk << 1) | g) ^ swz(r);                                                \
        af[mi] = *(const v4i*)(lds + (B) + r * 64 + slot * 16);                             \
      }                                                                                     \
      _Pragma("unroll") for (int ni = 0; ni < 2; ++ni) {                                    \
        int rb = wc * 64 + ni * 32 + am;                                                    \
        int slotb = ((kk << 1) | g) ^ swz(rb);                                              \
        bfi[ni] = *(const v4i*)(lds + (B) + 8192 + rb * 64 + slotb * 16);                   \
        bff[ni] = *(const v4i*)(lds + (B) + 16384 + rb * 64 + slotb * 16);                  \
      }                                                                                     \
      _Pragma("unroll") for (int mi = 0; mi < 2; ++mi)                                      \
        _Pragma("unroll") for (int ni = 0; ni < 2; ++ni) {                                  \
          acci[mi][ni] =                                                                    \
              __builtin_amdgcn_mfma_i32_32x32x32_i8(af[mi], bfi[ni], acci[mi][ni], 0, 0, 0);\
          accf[mi][ni] =                                                                    \
              __builtin_amdgcn_mfma_i32_32x32x32_i8(af[mi], bff[ni], accf[mi][ni], 0, 0, 0);\
        }                                                                                   \
    }                                                                                       \
  } while (0)

  STAGE_IF(0);
  STAGE_IF(24576);
  STAGE_IF(49152);
  SYNC_PIPE(12);
#pragma unroll 1
  for (int tt = 0; tt < 30; tt += 3) {
    COMPUTE_IF(0);
    SYNC_PIPE(6);
    if (tt + 3 < 32) STAGE_IF(0);
    COMPUTE_IF(24576);
    SYNC_PIPE(6);
    if (tt + 4 < 32) STAGE_IF(24576);
    COMPUTE_IF(49152);
    SYNC_PIPE(6);
    if (tt + 5 < 32) STAGE_IF(49152);
  }
  COMPUTE_IF(0);
  SYNC_PIPE(0);
  COMPUTE_IF(24576);
#undef STAGE_IF
#undef COMPUTE_IF

  float wmi = wmul[QW_I], wmf = wmul[QW_F];
  __syncthreads();  // all waves done with staging LDS before seg reuse
  float2* seglds = (float2*)lds;  // [seg 0..31][col 0..127], 32KB
#pragma unroll
  for (int mi = 0; mi < 2; ++mi) {
#pragma unroll
    for (int qh = 0; qh < 4; ++qh) {
      float segP[2], segH[2];
#pragma unroll
      for (int ql = 0; ql < 4; ++ql) {
        int q = qh * 4 + ql;
        int rloc = wr * 64 + mi * 32 + qh * 8 + g * 4 + ql;
        int rin = m0 + rloc;
        float ai = ainv[rin];
        float si = ai * wmi, sf = ai * wmf;
#pragma unroll
        for (int ni = 0; ni < 2; ++ni) {
          size_t idx = (size_t)rin * 2048 + n0 + wc * 64 + ni * 32 + am;
          float iv = (float)acci[mi][ni][q] * si;
          float fv = (float)accf[mi][ni][q] * sf;
          float a = fsig(fv);
          float s2 = iv * fsig(iv);
          float igv = s2 * (1.0f - a);
          __builtin_nontemporal_store(igv, &IG[idx]);
          __builtin_nontemporal_store(a, &AD[idx]);
          if (ql == 0) {
            segP[ni] = a;
            segH[ni] = igv;
          } else {
            segH[ni] = a * segH[ni] + igv;
            segP[ni] *= a;
          }
        }
      }
      int seg = wr * 16 + mi * 8 + qh * 2 + g;
#pragma unroll
      for (int ni = 0; ni < 2; ++ni)
        seglds[seg * 128 + wc * 64 + ni * 32 + am] = make_float2(segP[ni], segH[ni]);
    }
  }
  __syncthreads();
  if (t < 128) {
    int bb = mb / 36, lt = mb - bb * 36;
    int chain = bb * 2048 + n0 + t;
#pragma unroll
    for (int half = 0; half < 2; ++half) {
      float P = 1.f, H = 0.f;
#pragma unroll 1
      for (int s = 0; s < 16; ++s) {
        float2 e = seglds[(half * 16 + s) * 128 + t];
        H = e.x * H + e.y;
        P *= e.x;
      }
      int ck = lt * 2 + half;
      chA[(size_t)ck * 8192 + chain] = P;
      chH[(size_t)ck * 8192 + chain] = H;
    }
  }
}

// ------- cross-chunk combine, IN PLACE: chA[c] becomes the carry INTO chunk c -------
__global__ __launch_bounds__(256) void k_rec2(float* __restrict__ chA,
                                              const float* __restrict__ chH) {
  int chain = blockIdx.x * 256 + threadIdx.x;
  float carry = 0.f;
  for (int c = 0; c < 72; ++c) {
    size_t ix = (size_t)c * 8192 + chain;
    float a = chA[ix];
    float h = chH[ix];
    chA[ix] = carry;
    carry = a * carry + h;
  }
}

// ------- fused recurrence-replay + per-head rmsnorm + gate + full-row rmsnorm + quant -------
// Grid: 4 batches x 72 chunks (64 rows each). Block 1024 threads = 16 waves; thread t owns
// cols {2t, 2t+1}; wave w == head w (64 lanes x 2 cols = 128 cols). Walk 64 rows serially
// with h in registers (carry from k_rec2); per row: wave-level head-RMS reduce, block-level
// row ss/max reduce (2 barriers), gate with g*sig(g)*gnw, int8-quantize directly.
// o is never materialized. Next-row loads software-pipelined ahead of the reduces.
__global__ __launch_bounds__(1024) void k_rechq(const float* __restrict__ ig,
                                                const float* __restrict__ ad,
                                                const float* __restrict__ carry,
                                                const float* __restrict__ g,
                                                const float* __restrict__ gnw,
                                                int8_t* __restrict__ q,
                                                float* __restrict__ inv) {
  int blk = blockIdx.x;
  int b = blk / 72, c = blk - b * 72;
  int t = threadIdx.x;
  int col = t * 2;
  int wave = t >> 6;
  int gr0 = b * 4608 + c * 64;
  size_t base = (size_t)gr0 * 2048 + col;
  float h0 = carry[(size_t)c * 8192 + b * 2048 + col];
  float h1 = carry[(size_t)c * 8192 + b * 2048 + col + 1];
  float w0 = gnw[col & 127];
  float w1 = gnw[(col & 127) + 1];
  __shared__ float redS[16], redM[16], bcv[2];

  v2f igc = ldnt2(ig + base);
  v2f adc = ldnt2(ad + base);
  v2f gc = ldnt2(g + base);
#pragma unroll 1
  for (int s = 0; s < 64; ++s) {
    size_t nbase = base + 2048;
    v2f ign, adn, gn;
    if (s < 63) {
      ign = ldnt2(ig + nbase);
      adn = ldnt2(ad + nbase);
      gn = ldnt2(g + nbase);
    }
    h0 = adc[0] * h0 + igc[0];
    h1 = adc[1] * h1 + igc[1];
    float sh = h0 * h0 + h1 * h1;
#pragma unroll
    for (int o = 32; o; o >>= 1) sh += __shfl_xor(sh, o);
    float r = 1.0f / sqrtf(sh * (1.0f / 128.0f) + 1e-5f);
    float o20 = h0 * r * w0 * gc[0] * fsig(gc[0]);
    float o21 = h1 * r * w1 * gc[1] * fsig(gc[1]);
    float ss2 = o20 * o20 + o21 * o21;
    float mx = fmaxf(fabsf(o20), fabsf(o21));
#pragma unroll
    for (int o = 32; o; o >>= 1) {
      ss2 += __shfl_xor(ss2, o);
      mx = fmaxf(mx, __shfl_xor(mx, o));
    }
    if ((t & 63) == 0) { redS[wave] = ss2; redM[wave] = mx; }
    __syncthreads();
    if (t == 0) {
      float S = 0.f, M = 0.f;
#pragma unroll
      for (int wv = 0; wv < 16; ++wv) { S += redS[wv]; M = fmaxf(M, redM[wv]); }
      float rr = 1.0f / sqrtf(S * (1.0f / 2048.0f) + 1e-5f);
      float mxr = fmaxf(M * rr, 1e-5f);
      bcv[0] = rr;
      bcv[1] = 127.0f / mxr;
      inv[gr0 + s] = mxr * (1.0f / 127.0f);
    }
    __syncthreads();
    float rr = bcv[0], sc = bcv[1];
    int q0 = (int)rintf(o20 * rr * sc);
    int q1 = (int)rintf(o21 * rr * sc);
    q0 = q0 > 127 ? 127 : (q0 < -128 ? -128 : q0);
    q1 = q1 > 127 ? 127 : (q1 < -128 ? -128 : q1);
    unsigned short pk = (unsigned short)(((q1 & 0xff) << 8) | (q0 & 0xff));
    *(unsigned short*)(q + (size_t)(gr0 + s) * 2048 + col) = pk;
    base = nbase;
    igc = ign;
    adc = adn;
    gc = gn;
  }
}

// ---------------- launch ----------------
extern "C" void kernel_launch(void* const* d_in, const int* in_sizes, int n_in,
                              void* d_out, int out_size, void* d_ws, size_t ws_size,
                              hipStream_t stream) {
  const float* hid = (const float*)d_in[0];
  const float* enc = (const float*)d_in[1];
  const float* gnw = (const float*)d_in[14];
  Ptrs8 wp;
  wp.p[QW_Q] = (const float*)d_in[2];
  wp.p[QW_OUT] = (const float*)d_in[5];
  wp.p[QW_ADDQ] = (const float*)d_in[6];
  wp.p[QW_ADDOUT] = (const float*)d_in[9];
  wp.p[QW_I] = (const float*)d_in[10];
  wp.p[QW_F] = (const float*)d_in[11];
  wp.p[QW_G] = (const float*)d_in[12];
  wp.p[QW_O] = (const float*)d_in[13];
  float* out = (float*)d_out;

  char* ws = (char*)d_ws;
  float* bufA = (float*)ws;                       // q_joint -> ig -> (freed)
  float* bufB = bufA + 37748736;                  // a=sigmoid(f) -> attn_out
  int8_t* actq = (int8_t*)(bufB + 37748736);
  int8_t* wq = actq + 37748736;
  float* ainv = (float*)(wq + 33554432);
  double* wpart = (double*)(ainv + 18432);
  double* wqs = wpart + 8192;
  float* wmul = (float*)(wqs + 8);
  float* chA = wmul + 8;                          // 72*8192 = 589824 floats (reused as carries)
  float* chH = chA + 589824;                      // 72*8192
  if (ws_size < 379723872ULL) return;  // insufficient scratch

  RowMap idm{0x40000000, 0, 0};
  RowMap encoff{0x40000000, 0, 16384};  // identity + 16384 row offset (enc act rows)
  RowMap seqm{4096, 4608, 512};         // seq rows -> joint rows
  RowMap encm{512, 4608, 0};            // enc rows -> joint rows

  // 1. weight quantization (8 matrices)
  k_wabs<<<dim3(1024, 8), 256, 0, stream>>>(wp, wpart);
  k_wmean<<<8, 256, 0, stream>>>(wpart, wqs, wmul);
  k_wquant<<<dim3(1024, 8), 256, 0, stream>>>(wp, wqs, wq);
  // 2. quantize inputs
  k_actq<<<16384, 256, 0, stream>>>(hid, actq, ainv);
  k_actq<<<2048, 256, 0, stream>>>(enc, actq + (size_t)16384 * 2048, ainv + 16384);
  // 3. merged q_s + q_c -> q_joint (bufA); normal stores (actq reads next)
  k_gemm2<false><<<(128 + 16) * 8, 256, 0, stream>>>(
      actq, ainv, wq + (size_t)QW_Q * 4194304, QW_Q, idm, seqm, bufA, 128,
      wq + (size_t)QW_ADDQ * 4194304, QW_ADDQ, encoff, encm, bufA, 16, wmul);
  // 4. quantize q_joint
  k_actq<<<18432, 256, 0, stream>>>(bufA, actq, ainv);
  // 5. fused i+f GEMM + 64-row chunk summaries (ig -> bufA, a -> bufB, chA/chH; NT), g (NT)
  k_gemm_if<<<144 * 16, 256, 0, stream>>>(actq, ainv, wq + (size_t)QW_I * 4194304,
                                          wq + (size_t)QW_F * 4194304, wmul, bufA, bufB,
                                          chA, chH, 144);
  k_gemm<true><<<144 * 8, 256, 0, stream>>>(actq, ainv, wq + (size_t)QW_G * 4194304, wmul,
                                            QW_G, out, idm, idm, 144);
  // 6. cross-chunk combine (in-place: chA becomes carries)
  k_rec2<<<32, 256, 0, stream>>>(chA, chH);
  // 7. fused recurrence-replay + head-norm + gate + quant (ig=bufA, a=bufB, g=d_out -> actq)
  k_rechq<<<288, 1024, 0, stream>>>(bufA, bufB, chA, out, gnw, actq, ainv);
  // 8. o-projection -> bufB (normal stores; actq reads next)
  k_gemm<false><<<144 * 8, 256, 0, stream>>>(actq, ainv, wq + (size_t)QW_O * 4194304, wmul,
                                             QW_O, bufB, idm, idm, 144);
  // 9. quantize attn_out
  k_actq<<<18432, 256, 0, stream>>>(bufB, actq, ainv);
  // 10. merged final projections -> d_out (NT)
  k_gemm2<true><<<(128 + 16) * 8, 256, 0, stream>>>(
      actq, ainv, wq + (size_t)QW_OUT * 4194304, QW_OUT, seqm, idm, out, 128,
      wq + (size_t)QW_ADDOUT * 4194304, QW_ADDOUT, encm, idm, out + (size_t)33554432, 16, wmul);
}

// Round 14
// 896.516 us; speedup vs baseline: 1.0577x; 1.0577x over previous
//
#include <hip/hip_runtime.h>
#include <math.h>
#include <stdint.h>

#define D2 2048

typedef int v4i __attribute__((ext_vector_type(4)));
typedef int v16i __attribute__((ext_vector_type(16)));
typedef float v4f __attribute__((ext_vector_type(4)));

struct Ptrs8 { const float* p[8]; };
struct RowMap { int seg, jump, off; };

enum { QW_Q = 0, QW_OUT = 1, QW_ADDQ = 2, QW_ADDOUT = 3, QW_I = 4, QW_F = 5, QW_G = 6, QW_O = 7 };

__device__ __forceinline__ int rmap(RowMap m, int r) {
  return (r / m.seg) * m.jump + (r % m.seg) + m.off;
}

__device__ __forceinline__ void gload16(const void* g, void* l) {
  __builtin_amdgcn_global_load_lds((__attribute__((address_space(1))) void*)g,
                                   (__attribute__((address_space(3))) void*)l, 16, 0, 0);
}

__device__ __forceinline__ float fsig(float x) {
  return __builtin_amdgcn_rcpf(1.0f + __expf(-x));
}

template <bool NT>
__device__ __forceinline__ void stf(float* p, float v) {
  if (NT) __builtin_nontemporal_store(v, p);
  else *p = v;
}

__device__ __forceinline__ v4f ldnt4(const float* p) {
  return __builtin_nontemporal_load((const v4f*)p);
}

// Slot swizzle for 64B LDS rows (involution on stage+read sides).
__device__ __forceinline__ int swz(int r) { return ((r >> 1) & 3) ^ ((r >> 3) & 3); }

// XCD-chunked bijective grid swizzles, n-fast within a chunk.
__device__ __forceinline__ void gswz16(int nM, int& mb, int& nb) {  // nN = 16
  int bid = blockIdx.x;
  int wg = (bid & 7) * (nM << 1) + (bid >> 3);
  mb = wg >> 4;
  nb = wg & 15;
}
__device__ __forceinline__ void gswz8(int nM, int& mb, int& nb) {  // nN = 8
  int bid = blockIdx.x;
  int wg = (bid & 7) * nM + (bid >> 3);
  mb = wg >> 3;
  nb = wg & 7;
}

// ---------------- weight quantization ----------------
// k_wabs uses NORMAL loads so the 134MB of fp32 weights stay L3-resident; k_wquant's
// second pass then reads from L3, not HBM.
__global__ __launch_bounds__(256) void k_wabs(Ptrs8 wsrc, double* part) {
  int m = blockIdx.y;
  const float4* w4 = (const float4*)(wsrc.p[m] + (size_t)blockIdx.x * 4096 + threadIdx.x * 16);
  double s = 0.0;
#pragma unroll
  for (int j = 0; j < 4; ++j) {
    float4 v = w4[j];
    s += (double)fabsf(v.x) + (double)fabsf(v.y) + (double)fabsf(v.z) + (double)fabsf(v.w);
  }
#pragma unroll
  for (int o = 32; o; o >>= 1) s += __shfl_down(s, o);
  __shared__ double red[4];
  if ((threadIdx.x & 63) == 0) red[threadIdx.x >> 6] = s;
  __syncthreads();
  if (threadIdx.x == 0) part[(size_t)m * 1024 + blockIdx.x] = red[0] + red[1] + red[2] + red[3];
}

__global__ __launch_bounds__(256) void k_wmean(const double* part, double* wqs, float* wmul) {
  int m = blockIdx.x, t = threadIdx.x;
  const double* p = part + (size_t)m * 1024;
  double s = p[t] + p[t + 256] + p[t + 512] + p[t + 768];
#pragma unroll
  for (int o = 32; o; o >>= 1) s += __shfl_down(s, o);
  __shared__ double red[4];
  if ((t & 63) == 0) red[t >> 6] = s;
  __syncthreads();
  if (t == 0) {
    double mean = (red[0] + red[1] + red[2] + red[3]) * (1.0 / 4194304.0);
    double cl = mean > 1e-5 ? mean : 1e-5;
    wqs[m] = 1.0 / cl;
    wmul[m] = (float)cl;
  }
}

__global__ __launch_bounds__(256) void k_wquant(Ptrs8 wsrc, const double* wqs, int8_t* wq) {
  int m = blockIdx.y;
  double qs = wqs[m];
  size_t base = (size_t)blockIdx.x * 4096 + threadIdx.x * 16;
  const float* w0 = wsrc.p[m] + base;
  union { int8_t b[16]; int4 v; } u;
#pragma unroll
  for (int j = 0; j < 4; ++j) {
    v4f v = ldnt4(w0 + j * 4);  // hits L3 (warmed by k_wabs), no re-pollution
#pragma unroll
    for (int c = 0; c < 4; ++c) {
      int q = (int)rint((double)v[c] * qs);
      q = q > 1 ? 1 : (q < -1 ? -1 : q);
      u.b[j * 4 + c] = (int8_t)q;
    }
  }
  *(int4*)(wq + (size_t)m * 4194304 + base) = u.v;
}

// ---------------- activation rmsnorm + int8 quant ----------------
__device__ __forceinline__ void actq_body(const float* __restrict__ xr, int row,
                                          int8_t* __restrict__ q, float* __restrict__ inv,
                                          int t) {
  v4f a = ldnt4(xr);
  v4f b = ldnt4(xr + 4);
  float v[8] = {a[0], a[1], a[2], a[3], b[0], b[1], b[2], b[3]};
  float ss = 0.f, ma = 0.f;
#pragma unroll
  for (int j = 0; j < 8; ++j) { ss += v[j] * v[j]; ma = fmaxf(ma, fabsf(v[j])); }
#pragma unroll
  for (int o = 32; o; o >>= 1) { ss += __shfl_down(ss, o); ma = fmaxf(ma, __shfl_down(ma, o)); }
  __shared__ float rs[4], rm[4], bc[2];
  if ((t & 63) == 0) { rs[t >> 6] = ss; rm[t >> 6] = ma; }
  __syncthreads();
  if (t == 0) {
    float S = rs[0] + rs[1] + rs[2] + rs[3];
    float M = fmaxf(fmaxf(rm[0], rm[1]), fmaxf(rm[2], rm[3]));
    float r = 1.0f / sqrtf(S * (1.0f / 2048.0f) + 1e-5f);
    float mx = fmaxf(M * r, 1e-5f);
    bc[0] = r;
    bc[1] = 127.0f / mx;
    inv[row] = mx * (1.0f / 127.0f);
  }
  __syncthreads();
  float r = bc[0], s = bc[1];
  union { int8_t b8[8]; int2 p2; } u;
#pragma unroll
  for (int j = 0; j < 8; ++j) {
    float xn = v[j] * r;
    int qq = (int)rintf(xn * s);
    qq = qq > 127 ? 127 : (qq < -128 ? -128 : qq);
    u.b8[j] = (int8_t)qq;
  }
  ((int2*)(q + (size_t)row * D2))[t] = u.p2;
}

__global__ __launch_bounds__(256) void k_actq(const float* __restrict__ x, int8_t* __restrict__ q,
                                              float* __restrict__ inv) {
  int row = blockIdx.x, t = threadIdx.x;
  actq_body(x + (size_t)row * D2 + (size_t)t * 8, row, q, inv, t);
}

// merged input quant: rows 0..16383 from hid, 16384..18431 from enc
__global__ __launch_bounds__(256) void k_actq_in(const float* __restrict__ hid,
                                                 const float* __restrict__ enc,
                                                 int8_t* __restrict__ q,
                                                 float* __restrict__ inv) {
  int row = blockIdx.x, t = threadIdx.x;
  const float* src = row < 16384 ? hid + (size_t)row * D2
                                 : enc + (size_t)(row - 16384) * D2;
  actq_body(src + (size_t)t * 8, row, q, inv, t);
}

// ---------------- shared pipeline macros ----------------
#define SYNC_PIPE(N)                                          \
  do {                                                        \
    __builtin_amdgcn_sched_barrier(0);                        \
    asm volatile("s_waitcnt vmcnt(" #N ")" ::: "memory");     \
    __builtin_amdgcn_sched_barrier(0);                        \
    __builtin_amdgcn_s_barrier();                             \
    __builtin_amdgcn_sched_barrier(0);                        \
  } while (0)

// ------- 128x256 int8 GEMM main loop: wave tile 64x128, triple buffer, counted vmcnt -------
__device__ __forceinline__ void gemm_mainloop(const int8_t* __restrict__ Aq,
                                              const int8_t* __restrict__ Wq, int ga0, int ga1,
                                              int n0, int t, int8_t* lds, v16i acc[2][4]) {
  const int wid = t >> 6, lane = t & 63;
  const int wr = wid >> 1, wc = wid & 1, am = lane & 31, g = lane >> 5;
  const int arow = t >> 2;
  const int achk = ((t & 3) ^ swz(arow)) * 16;
  const int8_t* agp0 = Aq + (size_t)ga0 * 2048 + achk;
  const int8_t* agp1 = Aq + (size_t)ga1 * 2048 + achk;
  const int8_t* bgp0 = Wq + (size_t)(n0 + arow) * 2048 + achk;
  const int8_t* bgp1 = Wq + (size_t)(n0 + 64 + arow) * 2048 + achk;
  const int8_t* bgp2 = Wq + (size_t)(n0 + 128 + arow) * 2048 + achk;
  const int8_t* bgp3 = Wq + (size_t)(n0 + 192 + arow) * 2048 + achk;

#define STAGEW(B)                                                \
  do {                                                           \
    gload16(agp0, lds + (B) + wid * 1024);                       \
    gload16(agp1, lds + (B) + 4096 + wid * 1024);                \
    gload16(bgp0, lds + (B) + 8192 + wid * 1024);                \
    gload16(bgp1, lds + (B) + 12288 + wid * 1024);               \
    gload16(bgp2, lds + (B) + 16384 + wid * 1024);               \
    gload16(bgp3, lds + (B) + 20480 + wid * 1024);               \
    agp0 += 64; agp1 += 64;                                      \
    bgp0 += 64; bgp1 += 64; bgp2 += 64; bgp3 += 64;              \
  } while (0)

#define COMPUTEW(B)                                                                         \
  do {                                                                                      \
    _Pragma("unroll") for (int kk = 0; kk < 2; ++kk) {                                      \
      v4i af[2], bf[4];                                                                     \
      _Pragma("unroll") for (int mi = 0; mi < 2; ++mi) {                                    \
        int r = wr * 64 + mi * 32 + am;                                                     \
        int slot = ((kk << 1) | g) ^ swz(r);                                                \
        af[mi] = *(const v4i*)(lds + (B) + r * 64 + slot * 16);                             \
      }                                                                                     \
      _Pragma("unroll") for (int ni = 0; ni < 4; ++ni) {                                    \
        int rb = wc * 128 + ni * 32 + am;                                                   \
        int slotb = ((kk << 1) | g) ^ swz(rb);                                              \
        bf[ni] = *(const v4i*)(lds + (B) + 8192 + rb * 64 + slotb * 16);                    \
      }                                                                                     \
      _Pragma("unroll") for (int mi = 0; mi < 2; ++mi)                                      \
        _Pragma("unroll") for (int ni = 0; ni < 4; ++ni)                                    \
          acc[mi][ni] =                                                                     \
              __builtin_amdgcn_mfma_i32_32x32x32_i8(af[mi], bf[ni], acc[mi][ni], 0, 0, 0);  \
    }                                                                                       \
  } while (0)

  STAGEW(0);
  STAGEW(24576);
  STAGEW(49152);
  SYNC_PIPE(12);
#pragma unroll 1
  for (int tt = 0; tt < 30; tt += 3) {
    COMPUTEW(0);
    SYNC_PIPE(6);
    if (tt + 3 < 32) STAGEW(0);
    COMPUTEW(24576);
    SYNC_PIPE(6);
    if (tt + 4 < 32) STAGEW(24576);
    COMPUTEW(49152);
    SYNC_PIPE(6);
    if (tt + 5 < 32) STAGEW(49152);
  }
  COMPUTEW(0);
  SYNC_PIPE(0);
  COMPUTEW(24576);
#undef STAGEW
#undef COMPUTEW
}

template <bool NT>
__device__ __forceinline__ void gemm_body(const int8_t* Aq, const float* ainv, const int8_t* Wq,
                                          const float* wmul, int widx, float* C, RowMap inm,
                                          RowMap outm, int m0, int n0, int t, int8_t* lds) {
  int lane = t & 63, wid = t >> 6;
  int wr = wid >> 1, wc = wid & 1;
  int am = lane & 31, g = lane >> 5;
  int ga0 = rmap(inm, m0 + (t >> 2));
  int ga1 = rmap(inm, m0 + 64 + (t >> 2));

  v16i acc[2][4] = {};
  gemm_mainloop(Aq, Wq, ga0, ga1, n0, t, lds, acc);

  float wm = wmul[widx];
#pragma unroll
  for (int mi = 0; mi < 2; ++mi) {
#pragma unroll
    for (int q = 0; q < 16; ++q) {
      int rin = wr * 64 + mi * 32 + (q & 3) + ((q >> 2) * 8) + g * 4;
      int ra = rmap(inm, m0 + rin);
      int rc = rmap(outm, m0 + rin);
      float s = ainv[ra] * wm;
#pragma unroll
      for (int ni = 0; ni < 4; ++ni) {
        stf<NT>(&C[(size_t)rc * 2048 + n0 + wc * 128 + ni * 32 + am], (float)acc[mi][ni][q] * s);
      }
    }
  }
}

template <bool NT>
__global__ __launch_bounds__(256) void k_gemm(const int8_t* __restrict__ Aq,
                                              const float* __restrict__ ainv,
                                              const int8_t* __restrict__ Wq,
                                              const float* __restrict__ wmul, int widx,
                                              float* __restrict__ C, RowMap inm, RowMap outm,
                                              int nM) {
  __shared__ __align__(16) int8_t lds[73728];
  int mb, nb;
  gswz8(nM, mb, nb);
  gemm_body<NT>(Aq, ainv, Wq, wmul, widx, C, inm, outm, mb * 128, nb * 256, threadIdx.x, lds);
}

// Merged pair of GEMMs sharing one grid (big set 0 for mb<nM0, small set 1 after).
template <bool NT>
__global__ __launch_bounds__(256) void k_gemm2(const int8_t* __restrict__ Aq,
                                               const float* __restrict__ ainv,
                                               const int8_t* __restrict__ W0, int w0idx,
                                               RowMap inm0, RowMap outm0, float* __restrict__ C0,
                                               int nM0,
                                               const int8_t* __restrict__ W1, int w1idx,
                                               RowMap inm1, RowMap outm1, float* __restrict__ C1,
                                               int nM1, const float* __restrict__ wmul) {
  __shared__ __align__(16) int8_t lds[73728];
  int mb, nb;
  gswz8(nM0 + nM1, mb, nb);
  if (mb < nM0) {
    gemm_body<NT>(Aq, ainv, W0, wmul, w0idx, C0, inm0, outm0, mb * 128, nb * 256, threadIdx.x,
                  lds);
  } else {
    gemm_body<NT>(Aq, ainv, W1, wmul, w1idx, C1, inm1, outm1, (mb - nM0) * 128, nb * 256,
                  threadIdx.x, lds);
  }
}

// ------------- fused i+f GEMM + chunk-summary epilogue (replaces k_rec1) -------------
// LDS 72KB: 3 buffers x {A 8KB, Bi 8KB, Bf 8KB}. Counted vmcnt(6) steady state.
// Epilogue: a=sig(fv); ig=silu(iv)*(1-a); NT stores; composes the 128-row recurrence chunk
// summary (P=prod a, H=h from 0) for this block's 128 rows x 128 cols via reused LDS.
__global__ __launch_bounds__(256) void k_gemm_if(const int8_t* __restrict__ Aq,
                                                 const float* __restrict__ ainv,
                                                 const int8_t* __restrict__ Wi,
                                                 const int8_t* __restrict__ Wf,
                                                 const float* __restrict__ wmul,
                                                 float* __restrict__ IG, float* __restrict__ AD,
                                                 float* __restrict__ chA, float* __restrict__ chH,
                                                 int nM) {
  __shared__ __align__(16) int8_t lds[73728];
  int mb, nb;
  gswz16(nM, mb, nb);
  int m0 = mb * 128, n0 = nb * 128;
  int t = threadIdx.x;
  const int wid = t >> 6, lane = t & 63;
  const int wr = wid >> 1, wc = wid & 1, am = lane & 31, g = lane >> 5;
  const int arow = t >> 2;
  const int achk = ((t & 3) ^ swz(arow)) * 16;
  const int8_t* agp0 = Aq + (size_t)(m0 + arow) * 2048 + achk;
  const int8_t* agp1 = Aq + (size_t)(m0 + 64 + arow) * 2048 + achk;
  const int8_t* bip0 = Wi + (size_t)(n0 + arow) * 2048 + achk;
  const int8_t* bip1 = Wi + (size_t)(n0 + 64 + arow) * 2048 + achk;
  const int8_t* bfp0 = Wf + (size_t)(n0 + arow) * 2048 + achk;
  const int8_t* bfp1 = Wf + (size_t)(n0 + 64 + arow) * 2048 + achk;

  v16i acci[2][2] = {};
  v16i accf[2][2] = {};

#define STAGE_IF(B)                                                                   \
  do {                                                                                \
    gload16(agp0, lds + (B) + wid * 1024);                                            \
    gload16(agp1, lds + (B) + 4096 + wid * 1024);                                     \
    gload16(bip0, lds + (B) + 8192 + wid * 1024);                                     \
    gload16(bip1, lds + (B) + 12288 + wid * 1024);                                    \
    gload16(bfp0, lds + (B) + 16384 + wid * 1024);                                    \
    gload16(bfp1, lds + (B) + 20480 + wid * 1024);                                    \
    agp0 += 64; agp1 += 64; bip0 += 64; bip1 += 64; bfp0 += 64; bfp1 += 64;           \
  } while (0)

#define COMPUTE_IF(B)                                                                       \
  do {                                                                                      \
    _Pragma("unroll") for (int kk = 0; kk < 2; ++kk) {                                      \
      v4i af[2], bfi[2], bff[2];                                                            \
      _Pragma("unroll") for (int mi = 0; mi < 2; ++mi) {                                    \
        int r = wr * 64 + mi * 32 + am;                                                     \
        int slot = ((kk << 1) | g) ^ swz(r);                                                \
        af[mi] = *(const v4i*)(lds + (B) + r * 64 + slot * 16);                             \
      }                                                                                     \
      _Pragma("unroll") for (int ni = 0; ni < 2; ++ni) {                                    \
        int rb = wc * 64 + ni * 32 + am;                                                    \
        int slotb = ((kk << 1) | g) ^ swz(rb);                                              \
        bfi[ni] = *(const v4i*)(lds + (B) + 8192 + rb * 64 + slotb * 16);                   \
        bff[ni] = *(const v4i*)(lds + (B) + 16384 + rb * 64 + slotb * 16);                  \
      }                                                                                     \
      _Pragma("unroll") for (int mi = 0; mi < 2; ++mi)                                      \
        _Pragma("unroll") for (int ni = 0; ni < 2; ++ni) {                                  \
          acci[mi][ni] =                                                                    \
              __builtin_amdgcn_mfma_i32_32x32x32_i8(af[mi], bfi[ni], acci[mi][ni], 0, 0, 0);\
          accf[mi][ni] =                                                                    \
              __builtin_amdgcn_mfma_i32_32x32x32_i8(af[mi], bff[ni], accf[mi][ni], 0, 0, 0);\
        }                                                                                   \
    }                                                                                       \
  } while (0)

  STAGE_IF(0);
  STAGE_IF(24576);
  STAGE_IF(49152);
  SYNC_PIPE(12);
#pragma unroll 1
  for (int tt = 0; tt < 30; tt += 3) {
    COMPUTE_IF(0);
    SYNC_PIPE(6);
    if (tt + 3 < 32) STAGE_IF(0);
    COMPUTE_IF(24576);
    SYNC_PIPE(6);
    if (tt + 4 < 32) STAGE_IF(24576);
    COMPUTE_IF(49152);
    SYNC_PIPE(6);
    if (tt + 5 < 32) STAGE_IF(49152);
  }
  COMPUTE_IF(0);
  SYNC_PIPE(0);
  COMPUTE_IF(24576);
#undef STAGE_IF
#undef COMPUTE_IF

  float wmi = wmul[QW_I], wmf = wmul[QW_F];
  __syncthreads();  // all waves done with staging LDS before seg reuse
  float2* seglds = (float2*)lds;  // [seg 0..31][col 0..127], 32KB
#pragma unroll
  for (int mi = 0; mi < 2; ++mi) {
#pragma unroll
    for (int qh = 0; qh < 4; ++qh) {
      float segP[2], segH[2];
#pragma unroll
      for (int ql = 0; ql < 4; ++ql) {
        int q = qh * 4 + ql;
        int rloc = wr * 64 + mi * 32 + qh * 8 + g * 4 + ql;
        int rin = m0 + rloc;
        float ai = ainv[rin];
        float si = ai * wmi, sf = ai * wmf;
#pragma unroll
        for (int ni = 0; ni < 2; ++ni) {
          size_t idx = (size_t)rin * 2048 + n0 + wc * 64 + ni * 32 + am;
          float iv = (float)acci[mi][ni][q] * si;
          float fv = (float)accf[mi][ni][q] * sf;
          float a = fsig(fv);
          float s2 = iv * fsig(iv);
          float igv = s2 * (1.0f - a);
          __builtin_nontemporal_store(igv, &IG[idx]);
          __builtin_nontemporal_store(a, &AD[idx]);
          if (ql == 0) {
            segP[ni] = a;
            segH[ni] = igv;
          } else {
            segH[ni] = a * segH[ni] + igv;
            segP[ni] *= a;
          }
        }
      }
      int seg = wr * 16 + mi * 8 + qh * 2 + g;
#pragma unroll
      for (int ni = 0; ni < 2; ++ni)
        seglds[seg * 128 + wc * 64 + ni * 32 + am] = make_float2(segP[ni], segH[ni]);
    }
  }
  __syncthreads();
  if (t < 128) {
    float P = 1.f, H = 0.f;
#pragma unroll 1
    for (int s = 0; s < 32; ++s) {
      float2 e = seglds[s * 128 + t];
      H = e.x * H + e.y;
      P *= e.x;
    }
    int bb = mb / 36, ck = mb - bb * 36;
    int chain = bb * 2048 + n0 + t;
    chA[(size_t)ck * 8192 + chain] = P;
    chH[(size_t)ck * 8192 + chain] = H;
  }
}

// ---------------- cross-chunk combine + replay (chunk = 128 steps, 36 chunks) ----------------
__global__ __launch_bounds__(256) void k_rec2(const float* __restrict__ chA,
                                              const float* __restrict__ chH,
                                              float* __restrict__ chC) {
  int chain = blockIdx.x * 256 + threadIdx.x;
  float carry = 0.f;
  for (int c = 0; c < 36; ++c) {
    chC[(size_t)c * 8192 + chain] = carry;
    carry = chA[(size_t)c * 8192 + chain] * carry + chH[(size_t)c * 8192 + chain];
  }
}

__global__ __launch_bounds__(256) void k_rec3(float* __restrict__ io, const float* __restrict__ ad,
                                              const float* __restrict__ chC) {
  int tid = blockIdx.x * 256 + threadIdx.x;
  int chain = tid & 8191;
  int c = tid >> 13;  // 0..35
  int b = chain >> 11, d = chain & 2047;
  size_t base = ((size_t)b * 4608 + (size_t)c * 128) * 2048 + d;
  float h = chC[(size_t)c * 8192 + chain];
  for (int s = 0; s < 128; ++s) {
    float av = __builtin_nontemporal_load(ad + base);
    float iv = io[base];
    h = av * h + iv;
    io[base] = h;
    base += 2048;
  }
}

// ------- fused per-head rmsnorm + g*sig(g) gating + full-row rmsnorm + int8 quant -------
__global__ __launch_bounds__(256) void k_hnq(const float* __restrict__ o,
                                             const float* __restrict__ g,
                                             const float* __restrict__ gnw,
                                             int8_t* __restrict__ q, float* __restrict__ inv) {
  int row = blockIdx.x, t = threadIdx.x;
  size_t base = (size_t)row * D2 + (size_t)t * 8;
  v4f a = ldnt4(o + base);
  v4f b = ldnt4(o + base + 4);
  float v[8] = {a[0], a[1], a[2], a[3], b[0], b[1], b[2], b[3]};
  float ss = 0.f;
#pragma unroll
  for (int j = 0; j < 8; ++j) ss += v[j] * v[j];
  ss += __shfl_xor(ss, 1);
  ss += __shfl_xor(ss, 2);
  ss += __shfl_xor(ss, 4);
  ss += __shfl_xor(ss, 8);
  float r = 1.0f / sqrtf(ss * (1.0f / 128.0f) + 1e-5f);
  v4f ga = ldnt4(g + base);
  v4f gb = ldnt4(g + base + 4);
  float gv[8] = {ga[0], ga[1], ga[2], ga[3], gb[0], gb[1], gb[2], gb[3]};
  int j0 = (t & 15) * 8;
  float o2[8];
#pragma unroll
  for (int j = 0; j < 8; ++j) {
    float gg = gv[j];
    o2[j] = v[j] * r * gnw[j0 + j] * gg * fsig(gg);
  }
  float ss2 = 0.f, ma = 0.f;
#pragma unroll
  for (int j = 0; j < 8; ++j) { ss2 += o2[j] * o2[j]; ma = fmaxf(ma, fabsf(o2[j])); }
#pragma unroll
  for (int off = 32; off; off >>= 1) {
    ss2 += __shfl_down(ss2, off);
    ma = fmaxf(ma, __shfl_down(ma, off));
  }
  __shared__ float rs[4], rm[4], bc[2];
  if ((t & 63) == 0) { rs[t >> 6] = ss2; rm[t >> 6] = ma; }
  __syncthreads();
  if (t == 0) {
    float S = rs[0] + rs[1] + rs[2] + rs[3];
    float M = fmaxf(fmaxf(rm[0], rm[1]), fmaxf(rm[2], rm[3]));
    float rr = 1.0f / sqrtf(S * (1.0f / 2048.0f) + 1e-5f);
    float mx = fmaxf(M * rr, 1e-5f);
    bc[0] = rr;
    bc[1] = 127.0f / mx;
    inv[row] = mx * (1.0f / 127.0f);
  }
  __syncthreads();
  float rr = bc[0], s = bc[1];
  union { int8_t b8[8]; int2 p2; } u;
#pragma unroll
  for (int j = 0; j < 8; ++j) {
    float xn = o2[j] * rr;
    int qq = (int)rintf(xn * s);
    qq = qq > 127 ? 127 : (qq < -128 ? -128 : qq);
    u.b8[j] = (int8_t)qq;
  }
  ((int2*)(q + (size_t)row * D2))[t] = u.p2;
}

// ---------------- launch ----------------
extern "C" void kernel_launch(void* const* d_in, const int* in_sizes, int n_in,
                              void* d_out, int out_size, void* d_ws, size_t ws_size,
                              hipStream_t stream) {
  const float* hid = (const float*)d_in[0];
  const float* enc = (const float*)d_in[1];
  const float* gnw = (const float*)d_in[14];
  Ptrs8 wp;
  wp.p[QW_Q] = (const float*)d_in[2];
  wp.p[QW_OUT] = (const float*)d_in[5];
  wp.p[QW_ADDQ] = (const float*)d_in[6];
  wp.p[QW_ADDOUT] = (const float*)d_in[9];
  wp.p[QW_I] = (const float*)d_in[10];
  wp.p[QW_F] = (const float*)d_in[11];
  wp.p[QW_G] = (const float*)d_in[12];
  wp.p[QW_O] = (const float*)d_in[13];
  float* out = (float*)d_out;

  char* ws = (char*)d_ws;
  float* bufA = (float*)ws;                       // q_joint -> ig -> o -> (freed)
  float* bufB = bufA + 37748736;                  // a=sigmoid(f) -> attn_out
  int8_t* actq = (int8_t*)(bufB + 37748736);
  int8_t* wq = actq + 37748736;
  float* ainv = (float*)(wq + 33554432);
  double* wpart = (double*)(ainv + 18432);
  double* wqs = wpart + 8192;
  float* wmul = (float*)(wqs + 8);
  float* chA = wmul + 8;                          // 36*8192 used
  float* chH = chA + 524288;
  float* chC = chH + 524288;
  if (ws_size < 379723872ULL) return;  // insufficient scratch

  RowMap idm{0x40000000, 0, 0};
  RowMap encoff{0x40000000, 0, 16384};  // identity + 16384 row offset (enc act rows)
  RowMap seqm{4096, 4608, 512};         // seq rows -> joint rows
  RowMap encm{512, 4608, 0};            // enc rows -> joint rows

  // 1. weight quantization (8 matrices; wabs warms L3 for wquant)
  k_wabs<<<dim3(1024, 8), 256, 0, stream>>>(wp, wpart);
  k_wmean<<<8, 256, 0, stream>>>(wpart, wqs, wmul);
  k_wquant<<<dim3(1024, 8), 256, 0, stream>>>(wp, wqs, wq);
  // 2. quantize inputs (merged hid+enc, one dispatch)
  k_actq_in<<<18432, 256, 0, stream>>>(hid, enc, actq, ainv);
  // 3. merged q_s + q_c -> q_joint (bufA); normal stores (actq reads next)
  k_gemm2<false><<<(128 + 16) * 8, 256, 0, stream>>>(
      actq, ainv, wq + (size_t)QW_Q * 4194304, QW_Q, idm, seqm, bufA, 128,
      wq + (size_t)QW_ADDQ * 4194304, QW_ADDQ, encoff, encm, bufA, 16, wmul);
  // 4. quantize q_joint
  k_actq<<<18432, 256, 0, stream>>>(bufA, actq, ainv);
  // 5. fused i+f GEMM + chunk summaries (ig -> bufA, a -> bufB, chA/chH; NT), then g (NT)
  k_gemm_if<<<144 * 16, 256, 0, stream>>>(actq, ainv, wq + (size_t)QW_I * 4194304,
                                          wq + (size_t)QW_F * 4194304, wmul, bufA, bufB,
                                          chA, chH, 144);
  k_gemm<true><<<144 * 8, 256, 0, stream>>>(actq, ainv, wq + (size_t)QW_G * 4194304, wmul,
                                            QW_G, out, idm, idm, 144);
  // 6. recurrence: cross-chunk combine + replay (rec1 folded into gemm_if)
  k_rec2<<<32, 256, 0, stream>>>(chA, chH, chC);
  k_rec3<<<1152, 256, 0, stream>>>(bufA, bufB, chC);
  // 7. fused per-head norm + gate + quantize (o in bufA, g in d_out)
  k_hnq<<<18432, 256, 0, stream>>>(bufA, out, gnw, actq, ainv);
  // 8. o-projection -> bufB (normal stores; actq reads next)
  k_gemm<false><<<144 * 8, 256, 0, stream>>>(actq, ainv, wq + (size_t)QW_O * 4194304, wmul,
                                             QW_O, bufB, idm, idm, 144);
  // 9. quantize attn_out
  k_actq<<<18432, 256, 0, stream>>>(bufB, actq, ainv);
  // 10. merged final projections -> d_out (NT)
  k_gemm2<true><<<(128 + 16) * 8, 256, 0, stream>>>(
      actq, ainv, wq + (size_t)QW_OUT * 4194304, QW_OUT, seqm, idm, out, 128,
      wq + (size_t)QW_ADDOUT * 4194304, QW_ADDOUT, encm, idm, out + (size_t)33554432, 16, wmul);
}